// Round 1
// baseline (957.171 us; speedup 1.0000x reference)
//
#include <hip/hip_runtime.h>
#include <hip/hip_bf16.h>
#include <math.h>

#define B_    500
#define T_    100
#define I_    700
#define HALF_ 350
#define H_    512
#define O_    20
#define M_    (B_*T_)     // 50000 (b,t) pairs
#define BH_   (B_*H_)     // 256000

#define START_T  10
#define CODING_T 10
#define REMAIN_T 5

#define BM 64
#define BN 64
#define BKt 16

__device__ __forceinline__ float sigmoidf_(float x) {
  return 1.0f / (1.0f + expf(-x));
}

// ---------------- Pass 1: drive GEMM (fp32) ----------------
// dr1[tt][b][h] = sum_k input[b][t0+tt][k]      * W1[h][k]
// dr2[tt][b][h] = sum_k input[b][t0+tt][350+k]  * W2[h][k]
__global__ __launch_bounds__(256) void drive_gemm(
    const float* __restrict__ A, const float* __restrict__ W1,
    const float* __restrict__ W2, float* __restrict__ dr1,
    float* __restrict__ dr2, int t0, int Tc)
{
  __shared__ __align__(16) float As[BKt][BM + 4];  // k-major (transposed) tiles
  __shared__ __align__(16) float Bs[BKt][BN + 4];

  const int tid = threadIdx.x;
  const int h0 = blockIdx.x * BN;          // 8 n-tiles exactly cover H=512
  const int m0 = blockIdx.y * BM;
  const int Mc = B_ * Tc;

  const int tx = tid & 15;                 // n-dir thread
  const int ty = tid >> 4;                 // m-dir thread
  const int lrow = tid >> 2;               // loader row 0..63
  const int lk4  = (tid & 3) << 2;         // loader k offset 0,4,8,12

  float acc1[4][4] = {{0.f}}, acc2[4][4] = {{0.f}};

  const int mrow = m0 + lrow;
  const bool rowok = (mrow < Mc);
  int bi = 0, tt = 0;
  if (rowok) { bi = mrow / Tc; tt = mrow - bi * Tc; }
  const float* Arow  = A + ((size_t)bi * T_ + (size_t)(t0 + tt)) * I_;
  const float* Wrow1 = W1 + (size_t)(h0 + lrow) * HALF_;
  const float* Wrow2 = W2 + (size_t)(h0 + lrow) * HALF_;

#pragma unroll
  for (int phase = 0; phase < 2; ++phase) {
    const float* Wr = phase ? Wrow2 : Wrow1;
    const int abase = phase ? HALF_ : 0;
    for (int k0 = 0; k0 < HALF_; k0 += BKt) {
#pragma unroll
      for (int j = 0; j < 4; ++j) {
        const int kk = k0 + lk4 + j;
        const bool kok = (kk < HALF_);
        float av = (rowok && kok) ? Arow[abase + kk] : 0.0f;
        float wv = kok ? Wr[kk] : 0.0f;
        As[lk4 + j][lrow] = av;
        Bs[lk4 + j][lrow] = wv;
      }
      __syncthreads();
#pragma unroll
      for (int kk = 0; kk < BKt; ++kk) {
        const float4 a4 = *(const float4*)&As[kk][ty * 4];
        const float4 b4 = *(const float4*)&Bs[kk][tx * 4];
        if (phase == 0) {
          acc1[0][0] += a4.x * b4.x; acc1[0][1] += a4.x * b4.y; acc1[0][2] += a4.x * b4.z; acc1[0][3] += a4.x * b4.w;
          acc1[1][0] += a4.y * b4.x; acc1[1][1] += a4.y * b4.y; acc1[1][2] += a4.y * b4.z; acc1[1][3] += a4.y * b4.w;
          acc1[2][0] += a4.z * b4.x; acc1[2][1] += a4.z * b4.y; acc1[2][2] += a4.z * b4.z; acc1[2][3] += a4.z * b4.w;
          acc1[3][0] += a4.w * b4.x; acc1[3][1] += a4.w * b4.y; acc1[3][2] += a4.w * b4.z; acc1[3][3] += a4.w * b4.w;
        } else {
          acc2[0][0] += a4.x * b4.x; acc2[0][1] += a4.x * b4.y; acc2[0][2] += a4.x * b4.z; acc2[0][3] += a4.x * b4.w;
          acc2[1][0] += a4.y * b4.x; acc2[1][1] += a4.y * b4.y; acc2[1][2] += a4.y * b4.z; acc2[1][3] += a4.y * b4.w;
          acc2[2][0] += a4.z * b4.x; acc2[2][1] += a4.z * b4.y; acc2[2][2] += a4.z * b4.z; acc2[2][3] += a4.z * b4.w;
          acc2[3][0] += a4.w * b4.x; acc2[3][1] += a4.w * b4.y; acc2[3][2] += a4.w * b4.z; acc2[3][3] += a4.w * b4.w;
        }
      }
      __syncthreads();
    }
  }

#pragma unroll
  for (int i = 0; i < 4; ++i) {
    const int mp = m0 + ty * 4 + i;
    if (mp < Mc) {
      const int b = mp / Tc;
      const int ttl = mp - b * Tc;
      const size_t off = ((size_t)ttl * B_ + b) * H_ + h0 + tx * 4;
      *(float4*)(dr1 + off) = make_float4(acc1[i][0], acc1[i][1], acc1[i][2], acc1[i][3]);
      *(float4*)(dr2 + off) = make_float4(acc2[i][0], acc2[i][1], acc2[i][2], acc2[i][3]);
    }
  }
}

// ---------------- Pass 2: LIF scan (sequential in t, parallel over b,h) ----
__global__ __launch_bounds__(256) void scan_step(
    const float* __restrict__ dr1, const float* __restrict__ dr2,
    const float* __restrict__ v_init, const float* __restrict__ tau_n,
    const float* __restrict__ tau_m, float* __restrict__ st_d1,
    float* __restrict__ st_d2, float* __restrict__ st_v,
    unsigned char* __restrict__ spikes, int t0, int Tc)
{
  const int idx = blockIdx.x * 256 + threadIdx.x;  // (b,h) flat; grid exact
  const int h = idx & (H_ - 1);

  const float beta1 = sigmoidf_(tau_n[h]);
  const float beta2 = sigmoidf_(tau_n[H_ + h]);
  const float alpha = sigmoidf_(tau_m[h]);
  const float ob1 = 1.0f - beta1, ob2 = 1.0f - beta2, oa = 1.0f - alpha;

  float d1, d2, v, s;
  if (t0 == 0) {
    d1 = 0.0f; d2 = 0.0f; v = v_init[idx]; s = 0.0f;
  } else {
    d1 = st_d1[idx]; d2 = st_d2[idx]; v = st_v[idx];
    s = (float)spikes[(size_t)(t0 - 1) * BH_ + idx];
  }

  for (int tt = 0; tt < Tc; ++tt) {
    const size_t o = (size_t)tt * BH_ + idx;
    d1 = beta1 * d1 + ob1 * dr1[o];
    d2 = beta2 * d2 + ob2 * dr2[o];
    v = alpha * v + oa * (d1 + d2) - s;  // V_TH = 1
    s = (v > 1.0f) ? 1.0f : 0.0f;        // spike(v - V_TH): Heaviside(x>0)
    spikes[(size_t)(t0 + tt) * BH_ + idx] = (unsigned char)s;
  }
  st_d1[idx] = d1; st_d2[idx] = d2; st_v[idx] = v;
}

// ---------------- Pass 3: output GEMM (one wave per (b,t)) ----------------
__global__ __launch_bounds__(256) void out_gemm(
    const unsigned char* __restrict__ spikes, const float* __restrict__ Wout,
    const float* __restrict__ bout, float* __restrict__ oh)
{
  const int lane = threadIdx.x & 63;
  const int bt = blockIdx.x * 4 + (threadIdx.x >> 6);  // grid exact: 12500*4
  const int b = bt / T_, t = bt - b * T_;

  const unsigned char* srow = spikes + ((size_t)t * B_ + b) * H_;
  const uint2 sv = *(const uint2*)(srow + lane * 8);

  float acc[O_];
#pragma unroll
  for (int o = 0; o < O_; ++o) acc[o] = 0.0f;

#pragma unroll
  for (int j = 0; j < 8; ++j) {
    const unsigned sb = ((j < 4) ? (sv.x >> (8 * j)) : (sv.y >> (8 * (j - 4)))) & 255u;
    if (sb) {
      const int hh = lane * 8 + j;
#pragma unroll
      for (int o = 0; o < O_; ++o) acc[o] += Wout[o * H_ + hh];
    }
  }
#pragma unroll
  for (int o = 0; o < O_; ++o) {
#pragma unroll
    for (int off = 32; off > 0; off >>= 1) acc[o] += __shfl_down(acc[o], off);
  }
  if (lane == 0) {
    float* orow = oh + ((size_t)b * T_ + t) * O_;
#pragma unroll
    for (int o = 0; o < O_; ++o) orow[o] = acc[o] + bout[o];
  }
}

// ---------------- Pass 4: loss partials (double softmax CE + argmax) ------
__global__ __launch_bounds__(256) void loss_part(
    const float* __restrict__ oh, const int* __restrict__ target,
    float* __restrict__ partials, int nblocks)
{
  const int idx = blockIdx.x * 256 + threadIdx.x;  // (b,t) flat
  float lossc = 0.0f, corr = 0.0f;
  if (idx < M_) {
    const int t = idx % T_;
    const bool maskv = (t > START_T) && (((t - START_T) % (CODING_T + REMAIN_T)) > REMAIN_T);
    if (maskv) {
      const float* row = oh + (size_t)idx * O_;
      float r[O_];
#pragma unroll
      for (int o = 0; o < O_; ++o) r[o] = row[o];
      float m = r[0];
#pragma unroll
      for (int o = 1; o < O_; ++o) m = fmaxf(m, r[o]);
      const int tgt = target[idx];
      float e[O_], S = 0.0f, etgt = 0.0f;
#pragma unroll
      for (int o = 0; o < O_; ++o) {
        e[o] = expf(r[o] - m);
        S += e[o];
        etgt = (o == tgt) ? e[o] : etgt;
      }
      const float inv = 1.0f / S;
      const float pm = inv;  // max(p) = exp(0)/S
      float S2 = 0.0f;
#pragma unroll
      for (int o = 0; o < O_; ++o) S2 += expf(e[o] * inv - pm);
      const float lse = pm + logf(S2);
      lossc = (lse - etgt * inv) * (1.0f / (float)B_);
      int pred = 0;
      float bm = r[0];
#pragma unroll
      for (int o = 1; o < O_; ++o) { if (r[o] > bm) { bm = r[o]; pred = o; } }
      corr = (pred == tgt) ? 1.0f : 0.0f;
    }
  }
  __shared__ float sl[256], sc[256];
  sl[threadIdx.x] = lossc; sc[threadIdx.x] = corr;
  __syncthreads();
  for (int s = 128; s > 0; s >>= 1) {
    if (threadIdx.x < s) {
      sl[threadIdx.x] += sl[threadIdx.x + s];
      sc[threadIdx.x] += sc[threadIdx.x + s];
    }
    __syncthreads();
  }
  if (threadIdx.x == 0) {
    partials[blockIdx.x] = sl[0];
    partials[nblocks + blockIdx.x] = sc[0];
  }
}

__global__ __launch_bounds__(256) void loss_final(
    const float* __restrict__ partials, int np, float* __restrict__ out,
    float samples)
{
  float a = 0.0f, c = 0.0f;
  for (int i = threadIdx.x; i < np; i += 256) { a += partials[i]; c += partials[np + i]; }
  __shared__ float sl[256], sc[256];
  sl[threadIdx.x] = a; sc[threadIdx.x] = c;
  __syncthreads();
  for (int s = 128; s > 0; s >>= 1) {
    if (threadIdx.x < s) {
      sl[threadIdx.x] += sl[threadIdx.x + s];
      sc[threadIdx.x] += sc[threadIdx.x + s];
    }
    __syncthreads();
  }
  if (threadIdx.x == 0) {
    out[0] = sl[0];                         // total_loss
    out[1 + (size_t)M_ * O_] = sc[0];       // total_correct
    out[2 + (size_t)M_ * O_] = samples;     // total_samples (27000)
  }
}

extern "C" void kernel_launch(void* const* d_in, const int* in_sizes, int n_in,
                              void* d_out, int out_size, void* d_ws, size_t ws_size,
                              hipStream_t stream) {
  const float* input  = (const float*)d_in[0];
  const int*   target = (const int*)d_in[1];
  const float* v_init = (const float*)d_in[2];
  const float* W1     = (const float*)d_in[3];
  const float* W2     = (const float*)d_in[4];
  const float* tau_n  = (const float*)d_in[5];
  const float* tau_m  = (const float*)d_in[6];
  const float* Wout   = (const float*)d_in[7];
  const float* bout   = (const float*)d_in[8];
  float* out = (float*)d_out;
  float* oh  = out + 1;  // output_history region

  // workspace layout: dr1[Tc*BH] dr2[Tc*BH] st_d1[BH] st_d2[BH] st_v[BH]
  //                   spikes[T*BH u8] partials[2*NBL]
  const size_t plane = (size_t)BH_;
  static const int tc_opts[] = {100, 50, 25, 20, 10, 5, 4, 2, 1};
  int Tc = 1;
  for (int k = 0; k < 9; ++k) {
    const int c = tc_opts[k];
    const size_t need = (2 * (size_t)c * plane + 3 * plane) * 4 +
                        (size_t)T_ * plane + 8192;
    if (need <= ws_size) { Tc = c; break; }
  }

  float* dr1   = (float*)d_ws;
  float* dr2   = dr1 + (size_t)Tc * plane;
  float* st_d1 = dr2 + (size_t)Tc * plane;
  float* st_d2 = st_d1 + plane;
  float* st_v  = st_d2 + plane;
  unsigned char* spikes = (unsigned char*)(st_v + plane);
  float* partials = (float*)(spikes + (size_t)T_ * plane);

  const dim3 blk(256);
  const int nchunks = T_ / Tc;
  for (int c = 0; c < nchunks; ++c) {
    const int t0 = c * Tc;
    const dim3 g1(H_ / BN, (B_ * Tc + BM - 1) / BM);
    hipLaunchKernelGGL(drive_gemm, g1, blk, 0, stream, input, W1, W2, dr1, dr2, t0, Tc);
    hipLaunchKernelGGL(scan_step, dim3(BH_ / 256), blk, 0, stream,
                       dr1, dr2, v_init, tau_n, tau_m, st_d1, st_d2, st_v,
                       spikes, t0, Tc);
  }
  hipLaunchKernelGGL(out_gemm, dim3(M_ / 4), blk, 0, stream, spikes, Wout, bout, oh);

  const int NBL = (M_ + 255) / 256;
  hipLaunchKernelGGL(loss_part, dim3(NBL), blk, 0, stream, oh, target, partials, NBL);

  int mcount = 0;
  for (int t = 0; t < T_; ++t)
    if (t > START_T && ((t - START_T) % (CODING_T + REMAIN_T)) > REMAIN_T) mcount++;
  hipLaunchKernelGGL(loss_final, dim3(1), blk, 0, stream, partials, NBL,
                     out, (float)(mcount * B_));
}

// Round 2
// 271.205 us; speedup vs baseline: 3.5293x; 3.5293x over previous
//
#include <hip/hip_runtime.h>
#include <hip/hip_bf16.h>
#include <math.h>

#define B_    500
#define T_    100
#define I_    700
#define HALF_ 350
#define H_    512
#define O_    20
#define M_    (B_*T_)     // 50000
#define BH_   (B_*H_)     // 256000
#define MP_   50048       // M padded to multiple of 128
#define KP_   352         // HALF padded to multiple of 32
#define XK_   (2*KP_)     // 704

#define START_T  10
#define CODING_T 10
#define REMAIN_T 5

typedef __attribute__((ext_vector_type(8))) short short8v;
typedef __attribute__((ext_vector_type(8))) unsigned short ushort8v;
typedef __attribute__((ext_vector_type(4))) float f32x4;

__device__ __forceinline__ float sigmoidf_(float x) {
  return 1.0f / (1.0f + expf(-x));
}

__device__ __forceinline__ unsigned short f2bf(float f) {
  unsigned u = __float_as_uint(f);
  u = (u + 0x7fffu + ((u >> 16) & 1u)) >> 16;   // RTNE
  return (unsigned short)u;
}

__device__ __forceinline__ float bf2f(unsigned short b) {
  return __uint_as_float(((unsigned)b) << 16);
}

__device__ __forceinline__ void gload16(const unsigned short* g, unsigned short* l) {
  __builtin_amdgcn_global_load_lds(
      (const __attribute__((address_space(1))) unsigned int*)g,
      (__attribute__((address_space(3))) unsigned int*)l, 16, 0, 0);
}

// ---------- convert input fp32 -> padded bf16 Xb[MP_][704] ----------
__global__ __launch_bounds__(256) void convert_x(
    const float* __restrict__ in, unsigned short* __restrict__ xb)
{
  const long long idx = (long long)blockIdx.x * 256 + threadIdx.x;  // 8-elem chunk
  const int row = (int)(idx / (XK_ / 8));
  const int cc  = (int)(idx % (XK_ / 8)) * 8;
  ushort8v v;
  if (row < M_) {
    const float* src = in + (size_t)row * I_;
#pragma unroll
    for (int j = 0; j < 8; ++j) {
      const int c = cc + j;
      float f;
      if (c < KP_)       f = (c < HALF_) ? src[c] : 0.0f;
      else               f = (c - KP_ < HALF_) ? src[HALF_ + (c - KP_)] : 0.0f;
      v[j] = f2bf(f);
    }
  } else {
#pragma unroll
    for (int j = 0; j < 8; ++j) v[j] = 0;
  }
  *reinterpret_cast<ushort8v*>(xb + (size_t)row * XK_ + cc) = v;
}

// ---------- convert weights fp32 -> padded bf16 Wb[2][512][352] ----------
__global__ __launch_bounds__(256) void convert_w(
    const float* __restrict__ W1, const float* __restrict__ W2,
    unsigned short* __restrict__ wb)
{
  const int idx = blockIdx.x * 256 + threadIdx.x;  // 8-elem chunk; 45056 total
  const int ph  = idx / (H_ * (KP_ / 8));
  const int rem = idx % (H_ * (KP_ / 8));
  const int h   = rem / (KP_ / 8);
  const int cc  = (rem % (KP_ / 8)) * 8;
  const float* W = ph ? W2 : W1;
  ushort8v v;
#pragma unroll
  for (int j = 0; j < 8; ++j) {
    const int k = cc + j;
    v[j] = f2bf((k < HALF_) ? W[(size_t)h * HALF_ + k] : 0.0f);
  }
  *reinterpret_cast<ushort8v*>(wb + (((size_t)ph * H_ + h) * KP_) + cc) = v;
}

// ---------- MFMA drive GEMM: dr{1,2}[t][b][h] bf16 ----------
__global__ __launch_bounds__(256) void drive_mfma(
    const unsigned short* __restrict__ Xb, const unsigned short* __restrict__ Wb,
    unsigned short* __restrict__ dr1, unsigned short* __restrict__ dr2)
{
  __shared__ __align__(16) unsigned short As[128 * 32];
  __shared__ __align__(16) unsigned short Bs[128 * 32];

  const int tid  = threadIdx.x;
  const int lane = tid & 63;
  const int w    = tid >> 6;
  const int wr   = w >> 1, wc = w & 1;
  const int m0   = blockIdx.y * 128;
  const int h0   = blockIdx.x * 128;

  // staging: thread stages 2x16B of A and 2x16B of B per K-step
  const int lr = tid >> 2;            // loader row 0..63
  const int lc = (tid & 3) * 8;       // loader col {0,8,16,24}
  unsigned short* ldsA = As + tid * 8;          // chunk0 dest (wave-linear)
  unsigned short* ldsB = Bs + tid * 8;

  const int ar = wr * 64 + (lane & 15);
  const int br = wc * 64 + (lane & 15);
  const int kc = (lane >> 4) * 8;

  for (int phase = 0; phase < 2; ++phase) {
    f32x4 acc[4][4];
#pragma unroll
    for (int i = 0; i < 4; ++i)
#pragma unroll
      for (int j = 0; j < 4; ++j) acc[i][j] = f32x4{0.f, 0.f, 0.f, 0.f};

    const unsigned short* aSrc = Xb + (size_t)(m0 + lr) * XK_ + phase * KP_ + lc;
    const unsigned short* bSrc = Wb + ((size_t)phase * H_ + h0 + lr) * KP_ + lc;

    for (int k0 = 0; k0 < KP_; k0 += 32) {
      gload16(aSrc + k0, ldsA);
      gload16(aSrc + (size_t)64 * XK_ + k0, ldsA + 2048);
      gload16(bSrc + k0, ldsB);
      gload16(bSrc + (size_t)64 * KP_ + k0, ldsB + 2048);
      asm volatile("s_waitcnt vmcnt(0)" ::: "memory");
      __syncthreads();

      short8v a[4], b[4];
#pragma unroll
      for (int i = 0; i < 4; ++i)
        a[i] = *reinterpret_cast<const short8v*>(As + ((ar + i * 16) << 5) + kc);
#pragma unroll
      for (int j = 0; j < 4; ++j)
        b[j] = *reinterpret_cast<const short8v*>(Bs + ((br + j * 16) << 5) + kc);
#pragma unroll
      for (int i = 0; i < 4; ++i)
#pragma unroll
        for (int j = 0; j < 4; ++j)
          acc[i][j] = __builtin_amdgcn_mfma_f32_16x16x32_bf16(a[i], b[j], acc[i][j], 0, 0, 0);
      __syncthreads();
    }

    unsigned short* dst = phase ? dr2 : dr1;
#pragma unroll
    for (int i = 0; i < 4; ++i) {
      const int mb = m0 + wr * 64 + i * 16 + ((lane >> 4) << 2);
#pragma unroll
      for (int r = 0; r < 4; ++r) {
        const int m = mb + r;
        if (m < M_) {
          const int bb = m / T_;
          const int tt = m - bb * T_;
#pragma unroll
          for (int j = 0; j < 4; ++j) {
            const int h = h0 + wc * 64 + j * 16 + (lane & 15);
            dst[((size_t)tt * B_ + bb) * H_ + h] = f2bf(acc[i][j][r]);
          }
        }
      }
    }
  }
}

// ---------- LIF scan ----------
__global__ __launch_bounds__(256) void scan_step(
    const unsigned short* __restrict__ dr1, const unsigned short* __restrict__ dr2,
    const float* __restrict__ v_init, const float* __restrict__ tau_n,
    const float* __restrict__ tau_m, unsigned char* __restrict__ spikes)
{
  const int idx = blockIdx.x * 256 + threadIdx.x;  // (b,h) flat
  const int h = idx & (H_ - 1);

  const float beta1 = sigmoidf_(tau_n[h]);
  const float beta2 = sigmoidf_(tau_n[H_ + h]);
  const float alpha = sigmoidf_(tau_m[h]);
  const float ob1 = 1.0f - beta1, ob2 = 1.0f - beta2, oa = 1.0f - alpha;

  float d1 = 0.0f, d2 = 0.0f, v = v_init[idx], s = 0.0f;
  for (int t = 0; t < T_; ++t) {
    const size_t o = (size_t)t * BH_ + idx;
    d1 = beta1 * d1 + ob1 * bf2f(dr1[o]);
    d2 = beta2 * d2 + ob2 * bf2f(dr2[o]);
    v = alpha * v + oa * (d1 + d2) - s;   // V_TH = 1
    s = (v > 1.0f) ? 1.0f : 0.0f;
    spikes[o] = (unsigned char)s;
  }
}

// ---------- output GEMM (one wave per (b,t)) ----------
__global__ __launch_bounds__(256) void out_gemm(
    const unsigned char* __restrict__ spikes, const float* __restrict__ Wout,
    const float* __restrict__ bout, float* __restrict__ oh)
{
  const int lane = threadIdx.x & 63;
  const int bt = blockIdx.x * 4 + (threadIdx.x >> 6);
  const int b = bt / T_, t = bt - b * T_;

  const unsigned char* srow = spikes + ((size_t)t * B_ + b) * H_;
  const uint2 sv = *(const uint2*)(srow + lane * 8);

  float acc[O_];
#pragma unroll
  for (int o = 0; o < O_; ++o) acc[o] = 0.0f;

#pragma unroll
  for (int j = 0; j < 8; ++j) {
    const unsigned sb = ((j < 4) ? (sv.x >> (8 * j)) : (sv.y >> (8 * (j - 4)))) & 255u;
    if (sb) {
      const int hh = lane * 8 + j;
#pragma unroll
      for (int o = 0; o < O_; ++o) acc[o] += Wout[o * H_ + hh];
    }
  }
#pragma unroll
  for (int o = 0; o < O_; ++o) {
#pragma unroll
    for (int off = 32; off > 0; off >>= 1) acc[o] += __shfl_down(acc[o], off);
  }
  if (lane == 0) {
    float* orow = oh + ((size_t)b * T_ + t) * O_;
#pragma unroll
    for (int o = 0; o < O_; ++o) orow[o] = acc[o] + bout[o];
  }
}

// ---------- loss partials ----------
__global__ __launch_bounds__(256) void loss_part(
    const float* __restrict__ oh, const int* __restrict__ target,
    float* __restrict__ partials, int nblocks)
{
  const int idx = blockIdx.x * 256 + threadIdx.x;
  float lossc = 0.0f, corr = 0.0f;
  if (idx < M_) {
    const int t = idx % T_;
    const bool maskv = (t > START_T) && (((t - START_T) % (CODING_T + REMAIN_T)) > REMAIN_T);
    if (maskv) {
      const float* row = oh + (size_t)idx * O_;
      float r[O_];
#pragma unroll
      for (int o = 0; o < O_; ++o) r[o] = row[o];
      float m = r[0];
#pragma unroll
      for (int o = 1; o < O_; ++o) m = fmaxf(m, r[o]);
      const int tgt = target[idx];
      float e[O_], S = 0.0f, etgt = 0.0f;
#pragma unroll
      for (int o = 0; o < O_; ++o) {
        e[o] = expf(r[o] - m);
        S += e[o];
        etgt = (o == tgt) ? e[o] : etgt;
      }
      const float inv = 1.0f / S;
      const float pm = inv;
      float S2 = 0.0f;
#pragma unroll
      for (int o = 0; o < O_; ++o) S2 += expf(e[o] * inv - pm);
      const float lse = pm + logf(S2);
      lossc = (lse - etgt * inv) * (1.0f / (float)B_);
      int pred = 0;
      float bm = r[0];
#pragma unroll
      for (int o = 1; o < O_; ++o) { if (r[o] > bm) { bm = r[o]; pred = o; } }
      corr = (pred == tgt) ? 1.0f : 0.0f;
    }
  }
  __shared__ float sl[256], sc[256];
  sl[threadIdx.x] = lossc; sc[threadIdx.x] = corr;
  __syncthreads();
  for (int s = 128; s > 0; s >>= 1) {
    if (threadIdx.x < s) {
      sl[threadIdx.x] += sl[threadIdx.x + s];
      sc[threadIdx.x] += sc[threadIdx.x + s];
    }
    __syncthreads();
  }
  if (threadIdx.x == 0) {
    partials[blockIdx.x] = sl[0];
    partials[nblocks + blockIdx.x] = sc[0];
  }
}

__global__ __launch_bounds__(256) void loss_final(
    const float* __restrict__ partials, int np, float* __restrict__ out,
    float samples)
{
  float a = 0.0f, c = 0.0f;
  for (int i = threadIdx.x; i < np; i += 256) { a += partials[i]; c += partials[np + i]; }
  __shared__ float sl[256], sc[256];
  sl[threadIdx.x] = a; sc[threadIdx.x] = c;
  __syncthreads();
  for (int s = 128; s > 0; s >>= 1) {
    if (threadIdx.x < s) {
      sl[threadIdx.x] += sl[threadIdx.x + s];
      sc[threadIdx.x] += sc[threadIdx.x + s];
    }
    __syncthreads();
  }
  if (threadIdx.x == 0) {
    out[0] = sl[0];
    out[1 + (size_t)M_ * O_] = sc[0];
    out[2 + (size_t)M_ * O_] = samples;
  }
}

extern "C" void kernel_launch(void* const* d_in, const int* in_sizes, int n_in,
                              void* d_out, int out_size, void* d_ws, size_t ws_size,
                              hipStream_t stream) {
  const float* input  = (const float*)d_in[0];
  const int*   target = (const int*)d_in[1];
  const float* v_init = (const float*)d_in[2];
  const float* W1     = (const float*)d_in[3];
  const float* W2     = (const float*)d_in[4];
  const float* tau_n  = (const float*)d_in[5];
  const float* tau_m  = (const float*)d_in[6];
  const float* Wout   = (const float*)d_in[7];
  const float* bout   = (const float*)d_in[8];
  float* out = (float*)d_out;
  float* oh  = out + 1;

  // ws layout (bf16 everywhere): Xb[MP_*704] Wb[2*512*352] dr1[T*BH] dr2[T*BH]
  //                              spikes[T*BH u8] partials
  unsigned short* Xb  = (unsigned short*)d_ws;
  unsigned short* Wb  = Xb + (size_t)MP_ * XK_;
  unsigned short* dr1 = Wb + (size_t)2 * H_ * KP_;
  unsigned short* dr2 = dr1 + (size_t)T_ * BH_;
  unsigned char* spikes = (unsigned char*)(dr2 + (size_t)T_ * BH_);
  float* partials = (float*)(spikes + (size_t)T_ * BH_);

  const dim3 blk(256);

  const int ncx = (int)(((size_t)MP_ * XK_ / 8) / 256);  // exact: 17204
  hipLaunchKernelGGL(convert_x, dim3(ncx), blk, 0, stream, input, Xb);
  hipLaunchKernelGGL(convert_w, dim3((2 * H_ * KP_ / 8) / 256), blk, 0, stream, W1, W2, Wb);

  hipLaunchKernelGGL(drive_mfma, dim3(H_ / 128, MP_ / 128), blk, 0, stream, Xb, Wb, dr1, dr2);

  hipLaunchKernelGGL(scan_step, dim3(BH_ / 256), blk, 0, stream,
                     dr1, dr2, v_init, tau_n, tau_m, spikes);

  hipLaunchKernelGGL(out_gemm, dim3(M_ / 4), blk, 0, stream, spikes, Wout, bout, oh);

  const int NBL = (M_ + 255) / 256;
  hipLaunchKernelGGL(loss_part, dim3(NBL), blk, 0, stream, oh, target, partials, NBL);

  int mcount = 0;
  for (int t = 0; t < T_; ++t)
    if (t > START_T && ((t - START_T) % (CODING_T + REMAIN_T)) > REMAIN_T) mcount++;
  hipLaunchKernelGGL(loss_final, dim3(1), blk, 0, stream, partials, NBL,
                     out, (float)(mcount * B_));
}

// Round 3
// 234.881 us; speedup vs baseline: 4.0751x; 1.1547x over previous
//
#include <hip/hip_runtime.h>
#include <hip/hip_bf16.h>
#include <math.h>

#define B_    500
#define T_    100
#define I_    700
#define HALF_ 350
#define H_    512
#define O_    20
#define M_    (B_*T_)     // 50000
#define BH_   (B_*H_)     // 256000
#define TP_   112         // T padded to 7*16
#define KP_   352         // HALF padded to multiple of 32
#define XK_   (2*KP_)     // 704  (row width of padded Xb)
#define DRS_  114         // dr LDS t-stride (odd dword count: 228B = 57 dwords)

#define START_T  10
#define CODING_T 10
#define REMAIN_T 5

typedef __attribute__((ext_vector_type(8))) short short8v;
typedef __attribute__((ext_vector_type(8))) unsigned short ushort8v;
typedef __attribute__((ext_vector_type(4))) float f32x4;

__device__ __forceinline__ float sigmoidf_(float x) {
  return 1.0f / (1.0f + expf(-x));
}

__device__ __forceinline__ unsigned short f2bf(float f) {
  unsigned u = __float_as_uint(f);
  u = (u + 0x7fffu + ((u >> 16) & 1u)) >> 16;   // RTNE
  return (unsigned short)u;
}

__device__ __forceinline__ float bf2f(unsigned short b) {
  return __uint_as_float(((unsigned)b) << 16);
}

__device__ __forceinline__ void gload16(const unsigned short* g, unsigned short* l) {
  __builtin_amdgcn_global_load_lds(
      (const __attribute__((address_space(1))) unsigned int*)g,
      (__attribute__((address_space(3))) unsigned int*)l, 16, 0, 0);
}

// ---------- convert input fp32 -> padded bf16 Xb[500][112][704] ----------
// row t<100: cols 0..349 = X[b][t][0..349], 350..351 = 0,
//            cols 352..701 = X[b][t][350..699], 702..703 = 0.
// row t>=100: all zeros.
__global__ __launch_bounds__(256) void convert_x(
    const float* __restrict__ in, unsigned short* __restrict__ xb)
{
  const long long idx = (long long)blockIdx.x * 256 + threadIdx.x;  // 8-elem chunk
  const int row = (int)(idx / (XK_ / 8));       // 0..55999
  const int cc  = (int)(idx % (XK_ / 8)) * 8;
  const int b = row / TP_;
  const int t = row - b * TP_;
  ushort8v v;
  if (t < T_) {
    const float* src = in + ((size_t)b * T_ + t) * I_;
#pragma unroll
    for (int j = 0; j < 8; ++j) {
      const int c = cc + j;
      float f;
      if (c < KP_)  f = (c < HALF_) ? src[c] : 0.0f;
      else          f = ((c - KP_) < HALF_) ? src[HALF_ + (c - KP_)] : 0.0f;
      v[j] = f2bf(f);
    }
  } else {
#pragma unroll
    for (int j = 0; j < 8; ++j) v[j] = 0;
  }
  *reinterpret_cast<ushort8v*>(xb + (size_t)row * XK_ + cc) = v;
}

// ---------- convert weights fp32 -> padded bf16 Wb[2][512][352] ----------
__global__ __launch_bounds__(256) void convert_w(
    const float* __restrict__ W1, const float* __restrict__ W2,
    unsigned short* __restrict__ wb)
{
  const int idx = blockIdx.x * 256 + threadIdx.x;  // 8-elem chunk; 45056 total
  const int ph  = idx / (H_ * (KP_ / 8));
  const int rem = idx % (H_ * (KP_ / 8));
  const int h   = rem / (KP_ / 8);
  const int cc  = (rem % (KP_ / 8)) * 8;
  const float* W = ph ? W2 : W1;
  ushort8v v;
#pragma unroll
  for (int j = 0; j < 8; ++j) {
    const int k = cc + j;
    v[j] = f2bf((k < HALF_) ? W[(size_t)h * HALF_ + k] : 0.0f);
  }
  *reinterpret_cast<ushort8v*>(wb + (((size_t)ph * H_ + h) * KP_) + cc) = v;
}

// ---------- fused: drive GEMM (per-b) + in-LDS LIF scan -> spikes ----------
// block = (b, htile): computes dr1/dr2 [112 t][128 h] into LDS, scans t.
__global__ __launch_bounds__(256) void fused_drive_scan(
    const unsigned short* __restrict__ Xb, const unsigned short* __restrict__ Wb,
    const float* __restrict__ v_init, const float* __restrict__ tau_n,
    const float* __restrict__ tau_m, unsigned char* __restrict__ spikes)
{
  __shared__ __align__(16) unsigned short As[TP_ * 32];    // 7168 B
  __shared__ __align__(16) unsigned short Bs[128 * 32];    // 8192 B
  __shared__ __align__(16) unsigned short d1s[128 * DRS_]; // 29184 B
  __shared__ __align__(16) unsigned short d2s[128 * DRS_]; // 29184 B

  const int tid  = threadIdx.x;
  const int lane = tid & 63;
  const int w    = tid >> 6;

  // XCD-chunked swizzle: 4 h-tiles of each b land on the same XCD (L2 reuse).
  const int id   = blockIdx.x;                 // 0..1999 (2000 % 8 == 0)
  const int work = (id & 7) * 250 + (id >> 3);
  const int htile = work & 3;
  const int b     = work >> 2;
  const int h0    = htile * 128;

  // A staging: 112x32 bf16 = 448 16B-chunks. chunk c -> row=c>>2, kchunk=c&3
  const int cA0 = tid;               // 0..255
  const int cA1 = 256 + tid;         // valid while < 448  (waves 0..2)
  const unsigned short* aSrc0 =
      Xb + ((size_t)b * TP_ + (cA0 >> 2)) * XK_ + (cA0 & 3) * 8;
  const unsigned short* aSrc1 =
      Xb + ((size_t)b * TP_ + ((cA1 >> 2) < TP_ ? (cA1 >> 2) : 0)) * XK_ + (cA1 & 3) * 8;
  unsigned short* ldsA0 = As + (size_t)cA0 * 8;
  unsigned short* ldsA1 = As + (size_t)cA1 * 8;

  // B staging: 128x32 = 512 chunks
  const int cB0 = tid, cB1 = 256 + tid;
  const unsigned short* bSrc0 = Wb + ((size_t)(h0 + (cB0 >> 2))) * KP_ + (cB0 & 3) * 8;
  const unsigned short* bSrc1 = Wb + ((size_t)(h0 + (cB1 >> 2))) * KP_ + (cB1 & 3) * 8;
  unsigned short* ldsB0 = Bs + (size_t)cB0 * 8;
  unsigned short* ldsB1 = Bs + (size_t)cB1 * 8;

  const int arow = lane & 15;          // fragment row base (t)
  const int kc   = (lane >> 4) * 8;    // k offset within BK=32

#pragma unroll 1
  for (int phase = 0; phase < 2; ++phase) {
    f32x4 acc[7][2];
#pragma unroll
    for (int i = 0; i < 7; ++i) {
      acc[i][0] = f32x4{0.f, 0.f, 0.f, 0.f};
      acc[i][1] = f32x4{0.f, 0.f, 0.f, 0.f};
    }
    const size_t apo = (size_t)phase * KP_;
    const size_t bpo = (size_t)phase * H_ * KP_;

    for (int k0 = 0; k0 < KP_; k0 += 32) {
      gload16(aSrc0 + apo + k0, ldsA0);
      if (tid < 192) gload16(aSrc1 + apo + k0, ldsA1);
      gload16(bSrc0 + bpo + k0, ldsB0);
      gload16(bSrc1 + bpo + k0, ldsB1);
      asm volatile("s_waitcnt vmcnt(0)" ::: "memory");
      __syncthreads();

      short8v a[7], bb[2];
#pragma unroll
      for (int i = 0; i < 7; ++i)
        a[i] = *reinterpret_cast<const short8v*>(As + ((arow + i * 16) << 5) + kc);
#pragma unroll
      for (int j = 0; j < 2; ++j)
        bb[j] = *reinterpret_cast<const short8v*>(Bs + ((w * 32 + j * 16 + arow) << 5) + kc);
#pragma unroll
      for (int i = 0; i < 7; ++i) {
        acc[i][0] = __builtin_amdgcn_mfma_f32_16x16x32_bf16(a[i], bb[0], acc[i][0], 0, 0, 0);
        acc[i][1] = __builtin_amdgcn_mfma_f32_16x16x32_bf16(a[i], bb[1], acc[i][1], 0, 0, 0);
      }
      __syncthreads();
    }

    // dump acc -> dr LDS [h][t] (stride 114 elems = 57 dwords, conflict-light)
    unsigned short* ds = phase ? d2s : d1s;
#pragma unroll
    for (int i = 0; i < 7; ++i) {
      const int tb = i * 16 + ((lane >> 4) << 2);
#pragma unroll
      for (int j = 0; j < 2; ++j) {
        const int hl = w * 32 + j * 16 + (lane & 15);
#pragma unroll
        for (int r = 0; r < 4; ++r)
          ds[hl * DRS_ + tb + r] = f2bf(acc[i][j][r]);
      }
    }
  }
  __syncthreads();

  // ---- in-block LIF scan: thread = one h column ----
  if (tid < 128) {
    const int hg = h0 + tid;
    const float beta1 = sigmoidf_(tau_n[hg]);
    const float beta2 = sigmoidf_(tau_n[H_ + hg]);
    const float alpha = sigmoidf_(tau_m[hg]);
    const float ob1 = 1.0f - beta1, ob2 = 1.0f - beta2, oa = 1.0f - alpha;

    float d1 = 0.0f, d2 = 0.0f, s = 0.0f;
    float v = v_init[(size_t)b * H_ + hg];
    const unsigned short* r1 = d1s + tid * DRS_;
    const unsigned short* r2 = d2s + tid * DRS_;
    unsigned char* sp = spikes + (size_t)b * H_ + hg;
#pragma unroll 4
    for (int t = 0; t < T_; ++t) {
      d1 = beta1 * d1 + ob1 * bf2f(r1[t]);
      d2 = beta2 * d2 + ob2 * bf2f(r2[t]);
      v = alpha * v + oa * (d1 + d2) - s;   // V_TH = 1
      s = (v > 1.0f) ? 1.0f : 0.0f;
      sp[(size_t)t * BH_] = (unsigned char)s;
    }
  }
}

// ---------- output GEMM (one wave per (b,t)) ----------
__global__ __launch_bounds__(256) void out_gemm(
    const unsigned char* __restrict__ spikes, const float* __restrict__ Wout,
    const float* __restrict__ bout, float* __restrict__ oh)
{
  const int lane = threadIdx.x & 63;
  const int bt = blockIdx.x * 4 + (threadIdx.x >> 6);
  const int b = bt / T_, t = bt - b * T_;

  const unsigned char* srow = spikes + ((size_t)t * B_ + b) * H_;
  const uint2 sv = *(const uint2*)(srow + lane * 8);

  float acc[O_];
#pragma unroll
  for (int o = 0; o < O_; ++o) acc[o] = 0.0f;

#pragma unroll
  for (int j = 0; j < 8; ++j) {
    const unsigned sb = ((j < 4) ? (sv.x >> (8 * j)) : (sv.y >> (8 * (j - 4)))) & 255u;
    if (sb) {
      const int hh = lane * 8 + j;
#pragma unroll
      for (int o = 0; o < O_; ++o) acc[o] += Wout[o * H_ + hh];
    }
  }
#pragma unroll
  for (int o = 0; o < O_; ++o) {
#pragma unroll
    for (int off = 32; off > 0; off >>= 1) acc[o] += __shfl_down(acc[o], off);
  }
  if (lane == 0) {
    float* orow = oh + ((size_t)b * T_ + t) * O_;
#pragma unroll
    for (int o = 0; o < O_; ++o) orow[o] = acc[o] + bout[o];
  }
}

// ---------- loss partials ----------
__global__ __launch_bounds__(256) void loss_part(
    const float* __restrict__ oh, const int* __restrict__ target,
    float* __restrict__ partials, int nblocks)
{
  const int idx = blockIdx.x * 256 + threadIdx.x;
  float lossc = 0.0f, corr = 0.0f;
  if (idx < M_) {
    const int t = idx % T_;
    const bool maskv = (t > START_T) && (((t - START_T) % (CODING_T + REMAIN_T)) > REMAIN_T);
    if (maskv) {
      const float* row = oh + (size_t)idx * O_;
      float r[O_];
#pragma unroll
      for (int o = 0; o < O_; ++o) r[o] = row[o];
      float m = r[0];
#pragma unroll
      for (int o = 1; o < O_; ++o) m = fmaxf(m, r[o]);
      const int tgt = target[idx];
      float e[O_], S = 0.0f, etgt = 0.0f;
#pragma unroll
      for (int o = 0; o < O_; ++o) {
        e[o] = expf(r[o] - m);
        S += e[o];
        etgt = (o == tgt) ? e[o] : etgt;
      }
      const float inv = 1.0f / S;
      const float pm = inv;
      float S2 = 0.0f;
#pragma unroll
      for (int o = 0; o < O_; ++o) S2 += expf(e[o] * inv - pm);
      const float lse = pm + logf(S2);
      lossc = (lse - etgt * inv) * (1.0f / (float)B_);
      int pred = 0;
      float bm = r[0];
#pragma unroll
      for (int o = 1; o < O_; ++o) { if (r[o] > bm) { bm = r[o]; pred = o; } }
      corr = (pred == tgt) ? 1.0f : 0.0f;
    }
  }
  __shared__ float sl[256], sc[256];
  sl[threadIdx.x] = lossc; sc[threadIdx.x] = corr;
  __syncthreads();
  for (int s = 128; s > 0; s >>= 1) {
    if (threadIdx.x < s) {
      sl[threadIdx.x] += sl[threadIdx.x + s];
      sc[threadIdx.x] += sc[threadIdx.x + s];
    }
    __syncthreads();
  }
  if (threadIdx.x == 0) {
    partials[blockIdx.x] = sl[0];
    partials[nblocks + blockIdx.x] = sc[0];
  }
}

__global__ __launch_bounds__(256) void loss_final(
    const float* __restrict__ partials, int np, float* __restrict__ out,
    float samples)
{
  float a = 0.0f, c = 0.0f;
  for (int i = threadIdx.x; i < np; i += 256) { a += partials[i]; c += partials[np + i]; }
  __shared__ float sl[256], sc[256];
  sl[threadIdx.x] = a; sc[threadIdx.x] = c;
  __syncthreads();
  for (int s = 128; s > 0; s >>= 1) {
    if (threadIdx.x < s) {
      sl[threadIdx.x] += sl[threadIdx.x + s];
      sc[threadIdx.x] += sc[threadIdx.x + s];
    }
    __syncthreads();
  }
  if (threadIdx.x == 0) {
    out[0] = sl[0];
    out[1 + (size_t)M_ * O_] = sc[0];
    out[2 + (size_t)M_ * O_] = samples;
  }
}

extern "C" void kernel_launch(void* const* d_in, const int* in_sizes, int n_in,
                              void* d_out, int out_size, void* d_ws, size_t ws_size,
                              hipStream_t stream) {
  const float* input  = (const float*)d_in[0];
  const int*   target = (const int*)d_in[1];
  const float* v_init = (const float*)d_in[2];
  const float* W1     = (const float*)d_in[3];
  const float* W2     = (const float*)d_in[4];
  const float* tau_n  = (const float*)d_in[5];
  const float* tau_m  = (const float*)d_in[6];
  const float* Wout   = (const float*)d_in[7];
  const float* bout   = (const float*)d_in[8];
  float* out = (float*)d_out;
  float* oh  = out + 1;

  // ws layout: Xb[500*112*704 bf16] Wb[2*512*352 bf16] spikes[T*BH u8] partials
  unsigned short* Xb  = (unsigned short*)d_ws;
  unsigned short* Wb  = Xb + (size_t)B_ * TP_ * XK_;
  unsigned char* spikes = (unsigned char*)(Wb + (size_t)2 * H_ * KP_);
  float* partials = (float*)(spikes + (size_t)T_ * BH_);

  const dim3 blk(256);

  const int ncx = (int)(((size_t)B_ * TP_ * (XK_ / 8)) / 256);  // 19250 exact
  hipLaunchKernelGGL(convert_x, dim3(ncx), blk, 0, stream, input, Xb);
  hipLaunchKernelGGL(convert_w, dim3((2 * H_ * KP_ / 8) / 256), blk, 0, stream, W1, W2, Wb);

  hipLaunchKernelGGL(fused_drive_scan, dim3(2000), blk, 0, stream,
                     Xb, Wb, v_init, tau_n, tau_m, spikes);

  hipLaunchKernelGGL(out_gemm, dim3(M_ / 4), blk, 0, stream, spikes, Wout, bout, oh);

  const int NBL = (M_ + 255) / 256;
  hipLaunchKernelGGL(loss_part, dim3(NBL), blk, 0, stream, oh, target, partials, NBL);

  int mcount = 0;
  for (int t = 0; t < T_; ++t)
    if (t > START_T && ((t - START_T) % (CODING_T + REMAIN_T)) > REMAIN_T) mcount++;
  hipLaunchKernelGGL(loss_final, dim3(1), blk, 0, stream, partials, NBL,
                     out, (float)(mcount * B_));
}

// Round 4
// 219.780 us; speedup vs baseline: 4.3551x; 1.0687x over previous
//
#include <hip/hip_runtime.h>
#include <hip/hip_bf16.h>
#include <math.h>

#define B_    500
#define T_    100
#define I_    700
#define HALF_ 350
#define H_    512
#define O_    20
#define M_    (B_*T_)     // 50000
#define BH_   (B_*H_)     // 256000
#define TP_   112         // T padded to 7*16
#define KP_   352         // padded K per phase
#define ASTR_ 40          // A LDS row stride in shorts (80B: aligned, 2-way banks)
#define DRS_  114         // dr LDS t-stride (228B rows -> spread banks)
#define NB_   12500       // out_loss blocks

#define START_T  10
#define CODING_T 10
#define REMAIN_T 5

typedef __attribute__((ext_vector_type(8))) short short8v;
typedef __attribute__((ext_vector_type(8))) unsigned short ushort8v;
typedef __attribute__((ext_vector_type(4))) float f32x4;

__device__ __forceinline__ float sigmoidf_(float x) {
  return 1.0f / (1.0f + expf(-x));
}

__device__ __forceinline__ unsigned short f2bf(float f) {
  unsigned u = __float_as_uint(f);
  u = (u + 0x7fffu + ((u >> 16) & 1u)) >> 16;   // RTNE
  return (unsigned short)u;
}

__device__ __forceinline__ float bf2f(unsigned short b) {
  return __uint_as_float(((unsigned)b) << 16);
}

// ---------- convert weights fp32 -> padded bf16 Wb[2][512][352] ----------
// phase 0: kk<350 -> W1[kk], else 0      (A cols 0..351)
// phase 1: kk>=2  -> W2[kk-2], else 0    (A cols 348..699; 16B-aligned base)
__global__ __launch_bounds__(256) void convert_w(
    const float* __restrict__ W1, const float* __restrict__ W2,
    unsigned short* __restrict__ wb)
{
  const int idx = blockIdx.x * 256 + threadIdx.x;  // 8-elem chunk; 45056 total
  const int ph  = idx / (H_ * (KP_ / 8));
  const int rem = idx % (H_ * (KP_ / 8));
  const int h   = rem / (KP_ / 8);
  const int cc  = (rem % (KP_ / 8)) * 8;
  ushort8v v;
#pragma unroll
  for (int j = 0; j < 8; ++j) {
    const int kk = cc + j;
    float f;
    if (ph == 0) f = (kk < HALF_) ? W1[(size_t)h * HALF_ + kk] : 0.0f;
    else         f = (kk >= 2)    ? W2[(size_t)h * HALF_ + kk - 2] : 0.0f;
    v[j] = f2bf(f);
  }
  *reinterpret_cast<ushort8v*>(wb + (((size_t)ph * H_ + h) * KP_) + cc) = v;
}

// ---------- fused: drive GEMM (per-b) + in-LDS LIF scan -> spikes ----------
// block = (b, htile). A reg-staged fp32->bf16 into dbuf LDS; B direct to regs.
__global__ __launch_bounds__(256) void fused_drive_scan(
    const float* __restrict__ input, const unsigned short* __restrict__ Wb,
    const float* __restrict__ v_init, const float* __restrict__ tau_n,
    const float* __restrict__ tau_m, unsigned char* __restrict__ spikes)
{
  __shared__ __align__(16) unsigned short As[2 * TP_ * ASTR_];  // 17920 B
  __shared__ __align__(16) unsigned short d1s[128 * DRS_];      // 29184 B
  __shared__ __align__(16) unsigned short d2s[128 * DRS_];      // 29184 B

  const int tid  = threadIdx.x;
  const int lane = tid & 63;
  const int w    = tid >> 6;

  // XCD-chunked swizzle: 4 h-tiles of each b on one XCD (input L2 reuse).
  const int id    = blockIdx.x;                 // 0..1999 (2000 % 8 == 0)
  const int work  = (id & 7) * 250 + (id >> 3);
  const int htile = work & 3;
  const int b     = work >> 2;
  const int h0    = htile * 128;

  // A staging: thread tau<224 -> row t = tau>>1, half = tau&1 (16 cols)
  const int stT    = tid >> 1;
  const int stHalf = tid & 1;
  const bool stLd  = (tid < 224) && (stT < T_);
  const bool stZr  = (tid < 224) && (stT >= T_);
  const float* aBase = input + ((size_t)b * T_ + (stT < T_ ? stT : 0)) * I_ + stHalf * 16;
  unsigned short* aDstBase = As + stT * ASTR_ + stHalf * 16;

  // B fragment addressing (direct global): per wave rows w*32 + j*16 + (lane&15)
  const int brow = h0 + w * 32 + (lane & 15);
  const int kcS  = (lane >> 4) * 8;              // k offset in shorts
  const unsigned short* bBase0 = Wb + (size_t)brow * KP_ + kcS;
  const unsigned short* bBase1 = Wb + (size_t)(brow + 16) * KP_ + kcS;

  const int arow = lane & 15;

  f32x4 acc[7][2];
#pragma unroll
  for (int i = 0; i < 7; ++i) {
    acc[i][0] = f32x4{0.f, 0.f, 0.f, 0.f};
    acc[i][1] = f32x4{0.f, 0.f, 0.f, 0.f};
  }

  float4 aR0, aR1, aR2, aR3;
  short8v bC0, bC1, bN0, bN1;

  // prime k = 0 (phase 0, k0 = 0)
  if (stLd) {
    const float* ap = aBase;
    aR0 = *(const float4*)(ap + 0);
    aR1 = *(const float4*)(ap + 4);
    aR2 = *(const float4*)(ap + 8);
    aR3 = *(const float4*)(ap + 12);
  }
  bC0 = *reinterpret_cast<const short8v*>(bBase0);
  bC1 = *reinterpret_cast<const short8v*>(bBase1);

#pragma unroll 1
  for (int k = 0; k < 22; ++k) {
    const int buf = (k & 1) * (TP_ * ASTR_);
    // ---- stage A(k) into LDS (cvt waits on aR vmcnt) ----
    if (stLd) {
      ushort8v lo, hi;
      lo[0]=f2bf(aR0.x); lo[1]=f2bf(aR0.y); lo[2]=f2bf(aR0.z); lo[3]=f2bf(aR0.w);
      lo[4]=f2bf(aR1.x); lo[5]=f2bf(aR1.y); lo[6]=f2bf(aR1.z); lo[7]=f2bf(aR1.w);
      hi[0]=f2bf(aR2.x); hi[1]=f2bf(aR2.y); hi[2]=f2bf(aR2.z); hi[3]=f2bf(aR2.w);
      hi[4]=f2bf(aR3.x); hi[5]=f2bf(aR3.y); hi[6]=f2bf(aR3.z); hi[7]=f2bf(aR3.w);
      *reinterpret_cast<ushort8v*>(aDstBase + buf)     = lo;
      *reinterpret_cast<ushort8v*>(aDstBase + buf + 8) = hi;
    } else if (stZr) {
      ushort8v z = {0,0,0,0,0,0,0,0};
      *reinterpret_cast<ushort8v*>(aDstBase + buf)     = z;
      *reinterpret_cast<ushort8v*>(aDstBase + buf + 8) = z;
    }
    // ---- prefetch k+1 (stays in flight across raw barrier) ----
    if (k + 1 < 22) {
      const int kn  = k + 1;
      const int ph  = (kn >= 11);
      const int off = ph ? 348 : 0;                 // A col base (floats)
      const int k0  = (kn - ph * 11) * 32;
      if (stLd) {
        const float* ap = aBase + off + k0;
        aR0 = *(const float4*)(ap + 0);
        aR1 = *(const float4*)(ap + 4);
        aR2 = *(const float4*)(ap + 8);
        aR3 = *(const float4*)(ap + 12);
      }
      const size_t bo = (size_t)ph * H_ * KP_ + k0;
      bN0 = *reinterpret_cast<const short8v*>(bBase0 + bo);
      bN1 = *reinterpret_cast<const short8v*>(bBase1 + bo);
    }
    // ---- one barrier per step (A dbuf); vmcnt NOT drained ----
    asm volatile("s_waitcnt lgkmcnt(0)" ::: "memory");
    __builtin_amdgcn_s_barrier();
    asm volatile("" ::: "memory");
    // ---- read A fragments, MFMA ----
    short8v a[7];
#pragma unroll
    for (int i = 0; i < 7; ++i)
      a[i] = *reinterpret_cast<const short8v*>(As + buf + (arow + i * 16) * ASTR_ + kcS);
#pragma unroll
    for (int i = 0; i < 7; ++i) {
      acc[i][0] = __builtin_amdgcn_mfma_f32_16x16x32_bf16(a[i], bC0, acc[i][0], 0, 0, 0);
      acc[i][1] = __builtin_amdgcn_mfma_f32_16x16x32_bf16(a[i], bC1, acc[i][1], 0, 0, 0);
    }
    bC0 = bN0; bC1 = bN1;
    // ---- phase boundary: dump acc -> dr LDS, reset ----
    if (k == 10 || k == 21) {
      unsigned short* ds = (k == 10) ? d1s : d2s;
#pragma unroll
      for (int i = 0; i < 7; ++i) {
        const int tb = i * 16 + ((lane >> 4) << 2);
#pragma unroll
        for (int j = 0; j < 2; ++j) {
          const int hl = w * 32 + j * 16 + (lane & 15);
#pragma unroll
          for (int r = 0; r < 4; ++r)
            ds[hl * DRS_ + tb + r] = f2bf(acc[i][j][r]);
          acc[i][j] = f32x4{0.f, 0.f, 0.f, 0.f};
        }
      }
    }
  }
  __syncthreads();

  // ---- in-block LIF scan: thread = one h column ----
  if (tid < 128) {
    const int hg = h0 + tid;
    const float beta1 = sigmoidf_(tau_n[hg]);
    const float beta2 = sigmoidf_(tau_n[H_ + hg]);
    const float alpha = sigmoidf_(tau_m[hg]);
    const float ob1 = 1.0f - beta1, ob2 = 1.0f - beta2, oa = 1.0f - alpha;

    float d1 = 0.0f, d2 = 0.0f, s = 0.0f;
    float v = v_init[(size_t)b * H_ + hg];
    const unsigned short* r1 = d1s + tid * DRS_;
    const unsigned short* r2 = d2s + tid * DRS_;
    unsigned char* sp = spikes + (size_t)b * H_ + hg;
#pragma unroll 4
    for (int t = 0; t < T_; ++t) {
      d1 = beta1 * d1 + ob1 * bf2f(r1[t]);
      d2 = beta2 * d2 + ob2 * bf2f(r2[t]);
      v = alpha * v + oa * (d1 + d2) - s;   // V_TH = 1
      s = (v > 1.0f) ? 1.0f : 0.0f;
      sp[(size_t)t * BH_] = (unsigned char)s;
    }
  }
}

// ---------- fused output GEMM + loss partials (wave per (b,t)) ----------
__global__ __launch_bounds__(256) void out_loss(
    const unsigned char* __restrict__ spikes, const float* __restrict__ Wout,
    const float* __restrict__ bout, const int* __restrict__ target,
    float* __restrict__ oh, float* __restrict__ partials)
{
  const int lane = threadIdx.x & 63;
  const int widx = threadIdx.x >> 6;
  const int bt = blockIdx.x * 4 + widx;
  const int b = bt / T_, t = bt - b * T_;

  const unsigned char* srow = spikes + ((size_t)t * B_ + b) * H_;
  const uint2 sv = *(const uint2*)(srow + lane * 8);

  float acc[O_];
#pragma unroll
  for (int o = 0; o < O_; ++o) acc[o] = 0.0f;

#pragma unroll
  for (int j = 0; j < 8; ++j) {
    const unsigned sb = ((j < 4) ? (sv.x >> (8 * j)) : (sv.y >> (8 * (j - 4)))) & 255u;
    if (sb) {
      const int hh = lane * 8 + j;
#pragma unroll
      for (int o = 0; o < O_; ++o) acc[o] += Wout[o * H_ + hh];
    }
  }
#pragma unroll
  for (int o = 0; o < O_; ++o) {
#pragma unroll
    for (int off = 32; off > 0; off >>= 1) acc[o] += __shfl_down(acc[o], off);
  }

  __shared__ float sl[4], sc[4];
  if (lane == 0) {
    float r[O_];
    float* orow = oh + ((size_t)b * T_ + t) * O_;
#pragma unroll
    for (int o = 0; o < O_; ++o) { r[o] = acc[o] + bout[o]; orow[o] = r[o]; }

    float lossc = 0.0f, corr = 0.0f;
    const bool maskv = (t > START_T) && (((t - START_T) % (CODING_T + REMAIN_T)) > REMAIN_T);
    if (maskv) {
      float m = r[0];
#pragma unroll
      for (int o = 1; o < O_; ++o) m = fmaxf(m, r[o]);
      const int tgt = target[(size_t)b * T_ + t];
      float e[O_], S = 0.0f, etgt = 0.0f;
#pragma unroll
      for (int o = 0; o < O_; ++o) {
        e[o] = expf(r[o] - m);
        S += e[o];
        etgt = (o == tgt) ? e[o] : etgt;
      }
      const float inv = 1.0f / S;
      const float pm = inv;            // max(p) = exp(0)/S
      float S2 = 0.0f;
#pragma unroll
      for (int o = 0; o < O_; ++o) S2 += expf(e[o] * inv - pm);
      const float lse = pm + logf(S2);
      lossc = (lse - etgt * inv) * (1.0f / (float)B_);
      int pred = 0;
      float bm = r[0];
#pragma unroll
      for (int o = 1; o < O_; ++o) { if (r[o] > bm) { bm = r[o]; pred = o; } }
      corr = (pred == tgt) ? 1.0f : 0.0f;
    }
    sl[widx] = lossc; sc[widx] = corr;
  }
  __syncthreads();
  if (threadIdx.x == 0) {
    partials[blockIdx.x]       = sl[0] + sl[1] + sl[2] + sl[3];
    partials[NB_ + blockIdx.x] = sc[0] + sc[1] + sc[2] + sc[3];
  }
}

__global__ __launch_bounds__(256) void loss_final(
    const float* __restrict__ partials, float* __restrict__ out, float samples)
{
  float a = 0.0f, c = 0.0f;
  for (int i = threadIdx.x; i < NB_; i += 256) { a += partials[i]; c += partials[NB_ + i]; }
  __shared__ float sl[256], sc[256];
  sl[threadIdx.x] = a; sc[threadIdx.x] = c;
  __syncthreads();
  for (int s = 128; s > 0; s >>= 1) {
    if (threadIdx.x < s) {
      sl[threadIdx.x] += sl[threadIdx.x + s];
      sc[threadIdx.x] += sc[threadIdx.x + s];
    }
    __syncthreads();
  }
  if (threadIdx.x == 0) {
    out[0] = sl[0];
    out[1 + (size_t)M_ * O_] = sc[0];
    out[2 + (size_t)M_ * O_] = samples;
  }
}

extern "C" void kernel_launch(void* const* d_in, const int* in_sizes, int n_in,
                              void* d_out, int out_size, void* d_ws, size_t ws_size,
                              hipStream_t stream) {
  const float* input  = (const float*)d_in[0];
  const int*   target = (const int*)d_in[1];
  const float* v_init = (const float*)d_in[2];
  const float* W1     = (const float*)d_in[3];
  const float* W2     = (const float*)d_in[4];
  const float* tau_n  = (const float*)d_in[5];
  const float* tau_m  = (const float*)d_in[6];
  const float* Wout   = (const float*)d_in[7];
  const float* bout   = (const float*)d_in[8];
  float* out = (float*)d_out;
  float* oh  = out + 1;

  // ws layout: Wb[2*512*352 bf16] spikes[T*BH u8] partials[2*NB_ f32]
  unsigned short* Wb = (unsigned short*)d_ws;
  unsigned char* spikes = (unsigned char*)(Wb + (size_t)2 * H_ * KP_);
  float* partials = (float*)(spikes + (size_t)T_ * BH_);

  const dim3 blk(256);

  hipLaunchKernelGGL(convert_w, dim3((2 * H_ * KP_ / 8) / 256), blk, 0, stream,
                     W1, W2, Wb);

  hipLaunchKernelGGL(fused_drive_scan, dim3(2000), blk, 0, stream,
                     input, Wb, v_init, tau_n, tau_m, spikes);

  hipLaunchKernelGGL(out_loss, dim3(NB_), blk, 0, stream,
                     spikes, Wout, bout, target, oh, partials);

  int mcount = 0;
  for (int t = 0; t < T_; ++t)
    if (t > START_T && ((t - START_T) % (CODING_T + REMAIN_T)) > REMAIN_T) mcount++;
  hipLaunchKernelGGL(loss_final, dim3(1), blk, 0, stream, partials,
                     out, (float)(mcount * B_));
}

// Round 5
// 204.911 us; speedup vs baseline: 4.6712x; 1.0726x over previous
//
#include <hip/hip_runtime.h>
#include <hip/hip_bf16.h>
#include <math.h>

#define B_    500
#define T_    100
#define I_    700
#define HALF_ 350
#define H_    512
#define O_    20
#define M_    (B_*T_)     // 50000
#define BH_   (B_*H_)     // 256000
#define TP_   112         // T padded to 7*16
#define KP_   352         // padded K per phase
#define ASTR_ 40          // A LDS row stride shorts (80B: keeps b128 16B-aligned)
#define DRS_  116         // dr LDS t-stride shorts (232B: b64-aligned rows)
#define NB_   12500       // out_loss blocks

#define START_T  10
#define CODING_T 10
#define REMAIN_T 5

typedef __attribute__((ext_vector_type(8))) short short8v;
typedef __attribute__((ext_vector_type(8))) unsigned short ushort8v;
typedef __attribute__((ext_vector_type(4))) float f32x4;

__device__ __forceinline__ float sigmoidf_(float x) {
  return 1.0f / (1.0f + expf(-x));
}

// HW packed cvt: D[15:0]=bf16(lo), D[31:16]=bf16(hi), RTNE
__device__ __forceinline__ unsigned cvtpk(float lo, float hi) {
  unsigned r;
  asm("v_cvt_pk_bf16_f32 %0, %1, %2" : "=v"(r) : "v"(lo), "v"(hi));
  return r;
}

__device__ __forceinline__ unsigned short f2bf(float f) {
  unsigned u = __float_as_uint(f);
  u = (u + 0x7fffu + ((u >> 16) & 1u)) >> 16;   // RTNE (host-side-ish path, rare)
  return (unsigned short)u;
}

// ---------- convert weights fp32 -> padded bf16 Wb[2][512][352] ----------
// phase 0: kk<350 -> W1[kk], else 0      (A cols 0..351)
// phase 1: kk>=2  -> W2[kk-2], else 0    (A cols 348..699; 16B-aligned base)
__global__ __launch_bounds__(256) void convert_w(
    const float* __restrict__ W1, const float* __restrict__ W2,
    unsigned short* __restrict__ wb)
{
  const int idx = blockIdx.x * 256 + threadIdx.x;  // 8-elem chunk; 45056 total
  const int ph  = idx / (H_ * (KP_ / 8));
  const int rem = idx % (H_ * (KP_ / 8));
  const int h   = rem / (KP_ / 8);
  const int cc  = (rem % (KP_ / 8)) * 8;
  ushort8v v;
#pragma unroll
  for (int j = 0; j < 8; ++j) {
    const int kk = cc + j;
    float f;
    if (ph == 0) f = (kk < HALF_) ? W1[(size_t)h * HALF_ + kk] : 0.0f;
    else         f = (kk >= 2)    ? W2[(size_t)h * HALF_ + kk - 2] : 0.0f;
    v[j] = f2bf(f);
  }
  *reinterpret_cast<ushort8v*>(wb + (((size_t)ph * H_ + h) * KP_) + cc) = v;
}

// ---------- fused: drive GEMM (per-b) + in-LDS LIF scan -> spikes ----------
__global__ __launch_bounds__(256) void fused_drive_scan(
    const float* __restrict__ input, const unsigned short* __restrict__ Wb,
    const float* __restrict__ v_init, const float* __restrict__ tau_n,
    const float* __restrict__ tau_m, unsigned char* __restrict__ spikes)
{
  __shared__ __align__(16) unsigned short As[2 * TP_ * ASTR_];  // 17920 B
  __shared__ __align__(16) unsigned short d1s[128 * DRS_];      // 29696 B
  __shared__ __align__(16) unsigned short d2s[128 * DRS_];      // 29696 B

  const int tid  = threadIdx.x;
  const int lane = tid & 63;
  const int w    = tid >> 6;

  // XCD-chunked swizzle: 4 h-tiles of each b on one XCD (input L2 reuse).
  const int id    = blockIdx.x;                 // 0..1999 (2000 % 8 == 0)
  const int work  = (id & 7) * 250 + (id >> 3);
  const int htile = work & 3;
  const int b     = work >> 2;
  const int h0    = htile * 128;

  // A staging: thread tau<224 -> row t = tau>>1, half = tau&1 (16 cols)
  const int stT    = tid >> 1;
  const int stHalf = tid & 1;
  const bool stLd  = (tid < 224) && (stT < T_);
  const bool stZr  = (tid < 224) && (stT >= T_);
  const float* aBase = input + ((size_t)b * T_ + (stT < T_ ? stT : 0)) * I_ + stHalf * 16;
  unsigned short* aDstBase = As + stT * ASTR_ + stHalf * 16;

  // B fragment addressing (direct global; Wb is L2-resident)
  const int brow = h0 + w * 32 + (lane & 15);
  const int kcS  = (lane >> 4) * 8;
  const unsigned short* bBase0 = Wb + (size_t)brow * KP_ + kcS;
  const unsigned short* bBase1 = Wb + (size_t)(brow + 16) * KP_ + kcS;

  const int arow = lane & 15;

  f32x4 acc[7][2];
#pragma unroll
  for (int i = 0; i < 7; ++i) {
    acc[i][0] = f32x4{0.f, 0.f, 0.f, 0.f};
    acc[i][1] = f32x4{0.f, 0.f, 0.f, 0.f};
  }

  float4 aR0, aR1, aR2, aR3;
  short8v bC0, bC1, bN0, bN1;

  // ---- prologue: zero pad rows (both bufs), load+stage A(0), prime B ----
  if (stZr) {
    const uint4 z = {0, 0, 0, 0};
    *(uint4*)(aDstBase) = z;       *(uint4*)(aDstBase + 8) = z;
    *(uint4*)(aDstBase + TP_ * ASTR_) = z;
    *(uint4*)(aDstBase + TP_ * ASTR_ + 8) = z;
  }
  if (stLd) {
    aR0 = *(const float4*)(aBase + 0);
    aR1 = *(const float4*)(aBase + 4);
    aR2 = *(const float4*)(aBase + 8);
    aR3 = *(const float4*)(aBase + 12);
  }
  bC0 = *reinterpret_cast<const short8v*>(bBase0);
  bC1 = *reinterpret_cast<const short8v*>(bBase1);
  bN0 = *reinterpret_cast<const short8v*>(bBase0 + 32);
  bN1 = *reinterpret_cast<const short8v*>(bBase1 + 32);
  if (stLd) {
    const uint4 w0 = {cvtpk(aR0.x, aR0.y), cvtpk(aR0.z, aR0.w),
                      cvtpk(aR1.x, aR1.y), cvtpk(aR1.z, aR1.w)};
    const uint4 w1 = {cvtpk(aR2.x, aR2.y), cvtpk(aR2.z, aR2.w),
                      cvtpk(aR3.x, aR3.y), cvtpk(aR3.z, aR3.w)};
    *(uint4*)(aDstBase) = w0;
    *(uint4*)(aDstBase + 8) = w1;
    // prefetch A(1)
    aR0 = *(const float4*)(aBase + 32);
    aR1 = *(const float4*)(aBase + 36);
    aR2 = *(const float4*)(aBase + 40);
    aR3 = *(const float4*)(aBase + 44);
  }
  asm volatile("s_waitcnt lgkmcnt(0)" ::: "memory");
  __builtin_amdgcn_s_barrier();

#pragma unroll 1
  for (int k = 0; k < 22; ++k) {
    const int buf = (k & 1) * (TP_ * ASTR_);
    const int nbuf = ((k + 1) & 1) * (TP_ * ASTR_);
    // ---- read A fragments of buf k, MFMA (first: shortest path to matrix pipe)
    short8v a[7];
#pragma unroll
    for (int i = 0; i < 7; ++i)
      a[i] = *reinterpret_cast<const short8v*>(As + buf + (arow + i * 16) * ASTR_ + kcS);
#pragma unroll
    for (int i = 0; i < 7; ++i) {
      acc[i][0] = __builtin_amdgcn_mfma_f32_16x16x32_bf16(a[i], bC0, acc[i][0], 0, 0, 0);
      acc[i][1] = __builtin_amdgcn_mfma_f32_16x16x32_bf16(a[i], bC1, acc[i][1], 0, 0, 0);
    }
    bC0 = bN0; bC1 = bN1;
    // ---- stage buf k+1 from in-flight aR(k+1); prefetch k+2 ----
    if (k < 21) {
      if (stLd) {
        const uint4 w0 = {cvtpk(aR0.x, aR0.y), cvtpk(aR0.z, aR0.w),
                          cvtpk(aR1.x, aR1.y), cvtpk(aR1.z, aR1.w)};
        const uint4 w1 = {cvtpk(aR2.x, aR2.y), cvtpk(aR2.z, aR2.w),
                          cvtpk(aR3.x, aR3.y), cvtpk(aR3.z, aR3.w)};
        *(uint4*)(aDstBase + nbuf) = w0;
        *(uint4*)(aDstBase + nbuf + 8) = w1;
      }
      if (k < 20) {
        const int kn  = k + 2;
        const int ph  = (kn >= 11);
        const int off = ph ? 348 : 0;                 // A col base (floats)
        const int k0  = (kn - ph * 11) * 32;
        if (stLd) {
          const float* ap = aBase + off + k0;
          aR0 = *(const float4*)(ap + 0);
          aR1 = *(const float4*)(ap + 4);
          aR2 = *(const float4*)(ap + 8);
          aR3 = *(const float4*)(ap + 12);
        }
        const size_t bo = (size_t)ph * H_ * KP_ + k0;
        bN0 = *reinterpret_cast<const short8v*>(bBase0 + bo);
        bN1 = *reinterpret_cast<const short8v*>(bBase1 + bo);
      }
    }
    // ---- phase boundary: dump acc -> dr LDS (conflict-free b64), reset ----
    if (k == 10 || k == 21) {
      unsigned short* ds = (k == 10) ? d1s : d2s;
#pragma unroll
      for (int i = 0; i < 7; ++i) {
        const int tb = i * 16 + ((lane >> 4) << 2);
#pragma unroll
        for (int j = 0; j < 2; ++j) {
          const int hl = w * 32 + j * 16 + (lane & 15);
          const uint2 pk = {cvtpk(acc[i][j][0], acc[i][j][1]),
                            cvtpk(acc[i][j][2], acc[i][j][3])};
          *(uint2*)(ds + hl * DRS_ + tb) = pk;
          acc[i][j] = f32x4{0.f, 0.f, 0.f, 0.f};
        }
      }
    }
    asm volatile("s_waitcnt lgkmcnt(0)" ::: "memory");
    __builtin_amdgcn_s_barrier();
  }

  // ---- in-block LIF scan: thread = one h column ----
  if (tid < 128) {
    const int hg = h0 + tid;
    const float beta1 = sigmoidf_(tau_n[hg]);
    const float beta2 = sigmoidf_(tau_n[H_ + hg]);
    const float alpha = sigmoidf_(tau_m[hg]);
    const float ob1 = 1.0f - beta1, ob2 = 1.0f - beta2, oa = 1.0f - alpha;

    float d1 = 0.0f, d2 = 0.0f, s = 0.0f;
    float v = v_init[(size_t)b * H_ + hg];
    const unsigned short* r1 = d1s + tid * DRS_;
    const unsigned short* r2 = d2s + tid * DRS_;
    unsigned char* sp = spikes + (size_t)b * H_ + hg;
#pragma unroll 1
    for (int c = 0; c < 25; ++c) {                    // 25 x 4 = 100 steps
      const uint2 x1 = *(const uint2*)(r1 + c * 4);
      const uint2 x2 = *(const uint2*)(r2 + c * 4);
      const unsigned u1[2] = {x1.x, x1.y};
      const unsigned u2[2] = {x2.x, x2.y};
#pragma unroll
      for (int j = 0; j < 4; ++j) {
        const unsigned w1u = u1[j >> 1], w2u = u2[j >> 1];
        const float f1 = (j & 1) ? __uint_as_float(w1u & 0xffff0000u)
                                 : __uint_as_float(w1u << 16);
        const float f2 = (j & 1) ? __uint_as_float(w2u & 0xffff0000u)
                                 : __uint_as_float(w2u << 16);
        d1 = beta1 * d1 + ob1 * f1;
        d2 = beta2 * d2 + ob2 * f2;
        v = alpha * v + oa * (d1 + d2) - s;   // V_TH = 1
        s = (v > 1.0f) ? 1.0f : 0.0f;
        sp[(size_t)(c * 4 + j) * BH_] = (unsigned char)s;
      }
    }
  }
}

// ---------- fused output GEMM + loss partials (wave per (b,t)) ----------
__global__ __launch_bounds__(256) void out_loss(
    const unsigned char* __restrict__ spikes, const float* __restrict__ Wout,
    const float* __restrict__ bout, const int* __restrict__ target,
    float* __restrict__ oh, float* __restrict__ partials)
{
  const int lane = threadIdx.x & 63;
  const int widx = threadIdx.x >> 6;
  const int bt = blockIdx.x * 4 + widx;
  const int b = bt / T_, t = bt - b * T_;

  const unsigned char* srow = spikes + ((size_t)t * B_ + b) * H_;
  const uint2 sv = *(const uint2*)(srow + lane * 8);

  float acc[O_];
#pragma unroll
  for (int o = 0; o < O_; ++o) acc[o] = 0.0f;

#pragma unroll
  for (int j = 0; j < 8; ++j) {
    const unsigned sb = ((j < 4) ? (sv.x >> (8 * j)) : (sv.y >> (8 * (j - 4)))) & 255u;
    if (sb) {
      const int hh = lane * 8 + j;
#pragma unroll
      for (int o = 0; o < O_; ++o) acc[o] += Wout[o * H_ + hh];
    }
  }
#pragma unroll
  for (int o = 0; o < O_; ++o) {
#pragma unroll
    for (int off = 32; off > 0; off >>= 1) acc[o] += __shfl_down(acc[o], off);
  }

  __shared__ float sl[4], sc[4];
  if (lane == 0) {
    float r[O_];
    float* orow = oh + ((size_t)b * T_ + t) * O_;
#pragma unroll
    for (int o = 0; o < O_; ++o) { r[o] = acc[o] + bout[o]; orow[o] = r[o]; }

    float lossc = 0.0f, corr = 0.0f;
    const bool maskv = (t > START_T) && (((t - START_T) % (CODING_T + REMAIN_T)) > REMAIN_T);
    if (maskv) {
      float m = r[0];
#pragma unroll
      for (int o = 1; o < O_; ++o) m = fmaxf(m, r[o]);
      const int tgt = target[(size_t)b * T_ + t];
      float e[O_], S = 0.0f, etgt = 0.0f;
#pragma unroll
      for (int o = 0; o < O_; ++o) {
        e[o] = expf(r[o] - m);
        S += e[o];
        etgt = (o == tgt) ? e[o] : etgt;
      }
      const float inv = 1.0f / S;
      const float pm = inv;            // max(p) = exp(0)/S
      float S2 = 0.0f;
#pragma unroll
      for (int o = 0; o < O_; ++o) S2 += expf(e[o] * inv - pm);
      const float lse = pm + logf(S2);
      lossc = (lse - etgt * inv) * (1.0f / (float)B_);
      int pred = 0;
      float bm = r[0];
#pragma unroll
      for (int o = 1; o < O_; ++o) { if (r[o] > bm) { bm = r[o]; pred = o; } }
      corr = (pred == tgt) ? 1.0f : 0.0f;
    }
    sl[widx] = lossc; sc[widx] = corr;
  }
  __syncthreads();
  if (threadIdx.x == 0) {
    partials[blockIdx.x]       = sl[0] + sl[1] + sl[2] + sl[3];
    partials[NB_ + blockIdx.x] = sc[0] + sc[1] + sc[2] + sc[3];
  }
}

__global__ __launch_bounds__(256) void loss_final(
    const float* __restrict__ partials, float* __restrict__ out, float samples)
{
  float a = 0.0f, c = 0.0f;
  for (int i = threadIdx.x; i < NB_; i += 256) { a += partials[i]; c += partials[NB_ + i]; }
  __shared__ float sl[256], sc[256];
  sl[threadIdx.x] = a; sc[threadIdx.x] = c;
  __syncthreads();
  for (int s = 128; s > 0; s >>= 1) {
    if (threadIdx.x < s) {
      sl[threadIdx.x] += sl[threadIdx.x + s];
      sc[threadIdx.x] += sc[threadIdx.x + s];
    }
    __syncthreads();
  }
  if (threadIdx.x == 0) {
    out[0] = sl[0];
    out[1 + (size_t)M_ * O_] = sc[0];
    out[2 + (size_t)M_ * O_] = samples;
  }
}

extern "C" void kernel_launch(void* const* d_in, const int* in_sizes, int n_in,
                              void* d_out, int out_size, void* d_ws, size_t ws_size,
                              hipStream_t stream) {
  const float* input  = (const float*)d_in[0];
  const int*   target = (const int*)d_in[1];
  const float* v_init = (const float*)d_in[2];
  const float* W1     = (const float*)d_in[3];
  const float* W2     = (const float*)d_in[4];
  const float* tau_n  = (const float*)d_in[5];
  const float* tau_m  = (const float*)d_in[6];
  const float* Wout   = (const float*)d_in[7];
  const float* bout   = (const float*)d_in[8];
  float* out = (float*)d_out;
  float* oh  = out + 1;

  // ws layout: Wb[2*512*352 bf16] spikes[T*BH u8] partials[2*NB_ f32]
  unsigned short* Wb = (unsigned short*)d_ws;
  unsigned char* spikes = (unsigned char*)(Wb + (size_t)2 * H_ * KP_);
  float* partials = (float*)(spikes + (size_t)T_ * BH_);

  const dim3 blk(256);

  hipLaunchKernelGGL(convert_w, dim3((2 * H_ * KP_ / 8) / 256), blk, 0, stream,
                     W1, W2, Wb);

  hipLaunchKernelGGL(fused_drive_scan, dim3(2000), blk, 0, stream,
                     input, Wb, v_init, tau_n, tau_m, spikes);

  hipLaunchKernelGGL(out_loss, dim3(NB_), blk, 0, stream,
                     spikes, Wout, bout, target, oh, partials);

  int mcount = 0;
  for (int t = 0; t < T_; ++t)
    if (t > START_T && ((t - START_T) % (CODING_T + REMAIN_T)) > REMAIN_T) mcount++;
  hipLaunchKernelGGL(loss_final, dim3(1), blk, 0, stream, partials,
                     out, (float)(mcount * B_));
}